// Round 1
// 348.860 us; speedup vs baseline: 1.0408x; 1.0408x over previous
//
#include <hip/hip_runtime.h>

#define N_NODES 50000
#define N_EDGES 600000
#define HID 128
#define N_GRAPHS 512
#define BN_EPS 1e-5f
#define INV_N (1.0f / 50000.0f)

typedef __attribute__((ext_vector_type(8))) short bf16x8;
typedef __attribute__((ext_vector_type(4))) float f32x4;

__device__ __forceinline__ unsigned short f2b(float f) {
    unsigned u = __float_as_uint(f);
    return (unsigned short)((u + 0x7FFFu + ((u >> 16) & 1u)) >> 16);
}
__device__ __forceinline__ float b2f(unsigned short h) {
    return __uint_as_float(((unsigned)h) << 16);
}

// ---------------------------------------------------------------------------
// prep: convert x -> bf16 | transpose+convert 6 weight mats | degree count
// ---------------------------------------------------------------------------
#define CONVX_BLOCKS 6250
#define WCONV_BLOCKS 384
#define DEG_BLOCKS   2344
__global__ __launch_bounds__(256) void prep_kernel(
    const float* __restrict__ x, const float* __restrict__ gw1, const float* __restrict__ gw2,
    const float* __restrict__ swl, const float* __restrict__ swr, const int* __restrict__ dst,
    unsigned short* __restrict__ x16, unsigned short* __restrict__ wt, int* __restrict__ deg)
{
    int b = blockIdx.x;
    int t = threadIdx.x;
    if (b < CONVX_BLOCKS) {
        int gid = b * 256 + t;
        int i = gid >> 5, l = gid & 31;
        if (i >= N_NODES) return;
        int c0 = l * 4;
        float4 v = *(const float4*)(x + (size_t)i * 128 + c0);
        ushort4 o;
        o.x = f2b(v.x); o.y = f2b(v.y); o.z = f2b(v.z); o.w = f2b(v.w);
        *(ushort4*)(x16 + (size_t)i * 128 + c0) = o;
    } else if (b < CONVX_BLOCKS + WCONV_BLOCKS) {
        int gid = (b - CONVX_BLOCKS) * 256 + t;   // < 6*16384
        int m = gid >> 14;
        int e = gid & 16383;
        int k = e >> 7;
        int n = e & 127;
        const float* src = (m == 0) ? gw1 : (m == 1) ? gw2 : (m == 2) ? swl
                         : (m == 3) ? swr : (m == 4) ? (swl + 16384) : (swr + 16384);
        wt[m * 16384 + n * 128 + k] = f2b(src[k * 128 + n]);
    } else {
        int e = (b - CONVX_BLOCKS - WCONV_BLOCKS) * 256 + t;
        if (e < N_EDGES) atomicAdd(&deg[dst[e]], 1);
    }
}

// ---------------------------------------------------------------------------
// alloc (per-block scan + atomic base) + gstart (binary search), fused
// ---------------------------------------------------------------------------
#define ALLOC_BLOCKS 196
__global__ __launch_bounds__(256) void alloc_kernel(int* __restrict__ cursor,
                                                    int* __restrict__ row_beg,
                                                    float* __restrict__ inv_deg,
                                                    int* __restrict__ total,
                                                    const int* __restrict__ batch,
                                                    int* __restrict__ gstart) {
    if (blockIdx.x >= ALLOC_BLOCKS) {
        int g = (blockIdx.x - ALLOC_BLOCKS) * 256 + threadIdx.x;
        if (g > N_GRAPHS) return;
        int lo = 0, hi = N_NODES;
        while (lo < hi) {
            int mid = (lo + hi) >> 1;
            if (batch[mid] < g) lo = mid + 1; else hi = mid;
        }
        gstart[g] = lo;
        return;
    }
    __shared__ int tmp[256];
    __shared__ int base;
    int i = blockIdx.x * 256 + threadIdx.x;
    int d = (i < N_NODES) ? cursor[i] : 0;
    tmp[threadIdx.x] = d;
    __syncthreads();
#pragma unroll
    for (int off = 1; off < 256; off <<= 1) {
        int v = (threadIdx.x >= off) ? tmp[threadIdx.x - off] : 0;
        __syncthreads();
        tmp[threadIdx.x] += v;
        __syncthreads();
    }
    if (threadIdx.x == 255) base = atomicAdd(total, tmp[255]);
    __syncthreads();
    if (i < N_NODES) {
        int b = base + tmp[threadIdx.x] - d;
        row_beg[i] = b;
        cursor[i] = b;
        inv_deg[i] = 1.0f / fmaxf((float)d, 1.0f);
    }
}

__global__ void csr_fill_kernel(const int* __restrict__ src, const int* __restrict__ dst,
                                int* __restrict__ cursor, unsigned short* __restrict__ csr_src, int nE) {
    int e = blockIdx.x * blockDim.x + threadIdx.x;
    if (e < nE) {
        int pos = atomicAdd(&cursor[dst[e]], 1);
        csr_src[pos] = (unsigned short)src[e];
    }
}

// ---------------------------------------------------------------------------
// aggregate: agg[i] = (sum_e act(feat[src[e]])) * (MEAN? inv_deg : 1)
// AFF: act(v) = relu(v*c+s), affine computed in-kernel from stats
// HACT: also write hact[i] = act(feat[i])
// v2: block = 16 nodes; the block's contiguous CSR index range is staged in
// LDS (u16) so the gather's critical path is only the feature loads; 8-deep
// unroll keeps 8 independent 16B loads in flight per lane.
// ---------------------------------------------------------------------------
#define IDXCAP 2048
template<bool AFF, bool MEAN, bool HACT>
__global__ __launch_bounds__(256) void aggregate_kernel(
    const unsigned short* __restrict__ feat,
    const int* __restrict__ row_beg, const int* __restrict__ row_end,
    const unsigned short* __restrict__ csr_src,
    const float* __restrict__ stats, const float* __restrict__ gamma,
    const float* __restrict__ beta, const float* __restrict__ inv_deg,
    unsigned short* __restrict__ agg, unsigned short* __restrict__ hact, int n)
{
    __shared__ unsigned short idxbuf[IDXCAP];
    const int t = threadIdx.x;
    const int node0 = blockIdx.x * 16;
    const int node = node0 + (t >> 4);
    const int lane = t & 15;
    const int c0 = lane * 8;

    // block's contiguous CSR range (CSR rows are allocated contiguously)
    const int last = (node0 + 15 < n) ? node0 + 15 : n - 1;
    const int ebeg = row_beg[node0];
    const int ecnt = row_end[last] - ebeg;
    const bool lds_ok = (ecnt <= IDXCAP);
    if (lds_ok) {
        for (int i = t; i < ecnt; i += 256) idxbuf[i] = csr_src[ebeg + i];
    }
    __syncthreads();
    if (node >= n) return;

    float cc[8], ss[8];
    if (AFF) {
#pragma unroll
        for (int j = 0; j < 8; j++) {
            int col = c0 + j;
            float mu = stats[col] * INV_N;
            float var = stats[128 + col] * INV_N - mu * mu;
            float rs = rsqrtf(var + BN_EPS);
            float c = gamma[col] * rs;
            cc[j] = c;
            ss[j] = beta[col] - mu * c;
        }
    }

    float a[8];
#pragma unroll
    for (int j = 0; j < 8; j++) a[j] = 0.f;

    const int beg = row_beg[node];
    const int deg = row_end[node] - beg;

    if (lds_ok) {
        const int off = beg - ebeg;
        int e = 0;
        for (; e + 7 < deg; e += 8) {
            int s[8];
#pragma unroll
            for (int u = 0; u < 8; u++) s[u] = idxbuf[off + e + u];
            bf16x8 v[8];
#pragma unroll
            for (int u = 0; u < 8; u++)
                v[u] = *(const bf16x8*)(feat + (size_t)s[u] * 128 + c0);
#pragma unroll
            for (int u = 0; u < 8; u++) {
#pragma unroll
                for (int j = 0; j < 8; j++) {
                    float tv = b2f((unsigned short)v[u][j]);
                    if (AFF) tv = fmaxf(tv * cc[j] + ss[j], 0.f);
                    a[j] += tv;
                }
            }
        }
        for (; e + 3 < deg; e += 4) {
            int s[4];
#pragma unroll
            for (int u = 0; u < 4; u++) s[u] = idxbuf[off + e + u];
            bf16x8 v[4];
#pragma unroll
            for (int u = 0; u < 4; u++)
                v[u] = *(const bf16x8*)(feat + (size_t)s[u] * 128 + c0);
#pragma unroll
            for (int u = 0; u < 4; u++) {
#pragma unroll
                for (int j = 0; j < 8; j++) {
                    float tv = b2f((unsigned short)v[u][j]);
                    if (AFF) tv = fmaxf(tv * cc[j] + ss[j], 0.f);
                    a[j] += tv;
                }
            }
        }
        for (; e < deg; e++) {
            int s0 = idxbuf[off + e];
            bf16x8 v0 = *(const bf16x8*)(feat + (size_t)s0 * 128 + c0);
#pragma unroll
            for (int j = 0; j < 8; j++) {
                float tv = b2f((unsigned short)v0[j]);
                if (AFF) tv = fmaxf(tv * cc[j] + ss[j], 0.f);
                a[j] += tv;
            }
        }
    } else {
        // fallback (pathological degree skew): original global-index loop
        int e = beg, end = beg + deg;
        for (; e + 3 < end; e += 4) {
            int s0 = csr_src[e];
            int s1 = csr_src[e + 1];
            int s2 = csr_src[e + 2];
            int s3 = csr_src[e + 3];
            bf16x8 v0 = *(const bf16x8*)(feat + (size_t)s0 * 128 + c0);
            bf16x8 v1 = *(const bf16x8*)(feat + (size_t)s1 * 128 + c0);
            bf16x8 v2 = *(const bf16x8*)(feat + (size_t)s2 * 128 + c0);
            bf16x8 v3 = *(const bf16x8*)(feat + (size_t)s3 * 128 + c0);
#pragma unroll
            for (int j = 0; j < 8; j++) {
                float t0 = b2f((unsigned short)v0[j]);
                float t1 = b2f((unsigned short)v1[j]);
                float t2 = b2f((unsigned short)v2[j]);
                float t3 = b2f((unsigned short)v3[j]);
                if (AFF) {
                    t0 = fmaxf(t0 * cc[j] + ss[j], 0.f);
                    t1 = fmaxf(t1 * cc[j] + ss[j], 0.f);
                    t2 = fmaxf(t2 * cc[j] + ss[j], 0.f);
                    t3 = fmaxf(t3 * cc[j] + ss[j], 0.f);
                }
                a[j] += (t0 + t1) + (t2 + t3);
            }
        }
        for (; e < end; e++) {
            int s0 = csr_src[e];
            bf16x8 v0 = *(const bf16x8*)(feat + (size_t)s0 * 128 + c0);
#pragma unroll
            for (int j = 0; j < 8; j++) {
                float t0 = b2f((unsigned short)v0[j]);
                if (AFF) t0 = fmaxf(t0 * cc[j] + ss[j], 0.f);
                a[j] += t0;
            }
        }
    }

    if (MEAN) {
        float s = inv_deg[node];
#pragma unroll
        for (int j = 0; j < 8; j++) a[j] *= s;
    }
    bf16x8 o;
#pragma unroll
    for (int j = 0; j < 8; j++) o[j] = (short)f2b(a[j]);
    *(bf16x8*)(agg + (size_t)node * 128 + c0) = o;

    if (HACT) {
        bf16x8 v = *(const bf16x8*)(feat + (size_t)node * 128 + c0);
        bf16x8 h;
#pragma unroll
        for (int j = 0; j < 8; j++)
            h[j] = (short)f2b(fmaxf(b2f((unsigned short)v[j]) * cc[j] + ss[j], 0.f));
        *(bf16x8*)(hact + (size_t)node * 128 + c0) = h;
    }
}

// ---------------------------------------------------------------------------
// Fused GIN GEMM: Cb = bf16( relu((X+AGG)@W1 + b1) @ W2 + b2 ), stats fp32.
// ---------------------------------------------------------------------------
__global__ __launch_bounds__(256, 2) void gemm_gin_kernel(
    const unsigned short* __restrict__ X, const unsigned short* __restrict__ AGG,
    const unsigned short* __restrict__ W1t, const unsigned short* __restrict__ W2t,
    const float* __restrict__ b1, const float* __restrict__ b2,
    float* __restrict__ stats, unsigned short* __restrict__ Cb,
    int M, int ntiles)
{
    __shared__ unsigned short t1[32][136];
    __shared__ float red[2][128];

    const int t = threadIdx.x;
    const int wave = t >> 6;
    const int lane = t & 63;
    const int colhalf = wave & 1;
    const int rowpair = wave >> 1;
    const int m16 = lane & 15;
    const int quad = lane >> 4;
    const int k0 = quad * 8;
    const int colbase = colhalf * 64;
    const int lrow = rowpair * 16 + m16;

    const bf16x8 zero8 = {0, 0, 0, 0, 0, 0, 0, 0};

    bf16x8 w1f[4][4], w2f[4][4];
#pragma unroll
    for (int ct = 0; ct < 4; ct++) {
        int col = colbase + ct * 16 + m16;
#pragma unroll
        for (int kc = 0; kc < 4; kc++) {
            w1f[ct][kc] = *(const bf16x8*)(W1t + (size_t)col * 128 + kc * 32 + k0);
            w2f[ct][kc] = *(const bf16x8*)(W2t + (size_t)col * 128 + kc * 32 + k0);
        }
    }
    f32x4 bs1[4], bs2[4];
#pragma unroll
    for (int ct = 0; ct < 4; ct++) {
        bs1[ct] = *(const f32x4*)(b1 + colbase + ct * 16 + quad * 4);
        bs2[ct] = *(const f32x4*)(b2 + colbase + ct * 16 + quad * 4);
    }

    float psum[4][4], psq[4][4];
#pragma unroll
    for (int ct = 0; ct < 4; ct++)
#pragma unroll
        for (int r = 0; r < 4; r++) { psum[ct][r] = 0.f; psq[ct][r] = 0.f; }

    for (int tile = blockIdx.x; tile < ntiles; tile += gridDim.x) {
        int arow = tile * 32 + rowpair * 16 + m16;
        bool aok = arow < M;

        // A = bf16(x + agg)
        bf16x8 a[4];
#pragma unroll
        for (int kc = 0; kc < 4; kc++) {
            if (aok) {
                bf16x8 vx = *(const bf16x8*)(X + (size_t)arow * 128 + kc * 32 + k0);
                bf16x8 vg = *(const bf16x8*)(AGG + (size_t)arow * 128 + kc * 32 + k0);
                bf16x8 r;
#pragma unroll
                for (int i = 0; i < 8; i++)
                    r[i] = (short)f2b(b2f((unsigned short)vx[i]) + b2f((unsigned short)vg[i]));
                a[kc] = r;
            } else {
                a[kc] = zero8;
            }
        }

        // phase 1
        f32x4 acc[4];
#pragma unroll
        for (int ct = 0; ct < 4; ct++) acc[ct] = (f32x4){0.f, 0.f, 0.f, 0.f};
#pragma unroll
        for (int kc = 0; kc < 4; kc++)
#pragma unroll
            for (int ct = 0; ct < 4; ct++)
                acc[ct] = __builtin_amdgcn_mfma_f32_16x16x32_bf16(w1f[ct][kc], a[kc], acc[ct], 0, 0, 0);

        // T1 = relu(acc + b1) -> LDS
        __syncthreads();   // previous tile's t1 reads done
#pragma unroll
        for (int ct = 0; ct < 4; ct++) {
            f32x4 v = acc[ct] + bs1[ct];
            ushort4 o;
            o.x = f2b(fmaxf(v[0], 0.f));
            o.y = f2b(fmaxf(v[1], 0.f));
            o.z = f2b(fmaxf(v[2], 0.f));
            o.w = f2b(fmaxf(v[3], 0.f));
            *(ushort4*)&t1[lrow][colbase + ct * 16 + quad * 4] = o;
        }
        __syncthreads();

        // phase 2: A-frags from LDS
        bf16x8 ta[4];
#pragma unroll
        for (int kc = 0; kc < 4; kc++)
            ta[kc] = *(const bf16x8*)&t1[lrow][kc * 32 + k0];

        f32x4 acc2[4];
#pragma unroll
        for (int ct = 0; ct < 4; ct++) acc2[ct] = (f32x4){0.f, 0.f, 0.f, 0.f};
#pragma unroll
        for (int kc = 0; kc < 4; kc++)
#pragma unroll
            for (int ct = 0; ct < 4; ct++)
                acc2[ct] = __builtin_amdgcn_mfma_f32_16x16x32_bf16(w2f[ct][kc], ta[kc], acc2[ct], 0, 0, 0);

        int orow = arow;
        if (orow < M) {
#pragma unroll
            for (int ct = 0; ct < 4; ct++) {
                f32x4 v = acc2[ct] + bs2[ct];
                int col = colbase + ct * 16 + quad * 4;
#pragma unroll
                for (int r = 0; r < 4; r++) { psum[ct][r] += v[r]; psq[ct][r] += v[r] * v[r]; }
                ushort4 o;
                o.x = f2b(v[0]); o.y = f2b(v[1]); o.z = f2b(v[2]); o.w = f2b(v[3]);
                *(ushort4*)(Cb + (size_t)orow * 128 + col) = o;
            }
        }
    }

    // stats flush
#pragma unroll
    for (int ct = 0; ct < 4; ct++)
#pragma unroll
        for (int r = 0; r < 4; r++) {
#pragma unroll
            for (int mask = 1; mask <= 8; mask <<= 1) {
                psum[ct][r] += __shfl_xor(psum[ct][r], mask, 64);
                psq[ct][r]  += __shfl_xor(psq[ct][r], mask, 64);
            }
        }
    __syncthreads();
    if (m16 == 0) {
#pragma unroll
        for (int ct = 0; ct < 4; ct++)
#pragma unroll
            for (int r = 0; r < 4; r++)
                red[rowpair][colbase + ct * 16 + quad * 4 + r] = psum[ct][r];
    }
    __syncthreads();
    if (t < 128) atomicAdd(&stats[t], red[0][t] + red[1][t]);
    __syncthreads();
    if (m16 == 0) {
#pragma unroll
        for (int ct = 0; ct < 4; ct++)
#pragma unroll
            for (int r = 0; r < 4; r++)
                red[rowpair][colbase + ct * 16 + quad * 4 + r] = psq[ct][r];
    }
    __syncthreads();
    if (t < 128) atomicAdd(&stats[128 + t], red[0][t] + red[1][t]);
}

// ---------------------------------------------------------------------------
// Dual-matrix GEMM (SAGE): Cb = bf16(A1@W1 + A2@W2 + bias), stats fp32.
// ---------------------------------------------------------------------------
__global__ __launch_bounds__(256) void gemm_dual_kernel(
    const unsigned short* __restrict__ A1, const unsigned short* __restrict__ A2,
    const unsigned short* __restrict__ W1t, const unsigned short* __restrict__ W2t,
    const float* __restrict__ bias, float* __restrict__ stats,
    unsigned short* __restrict__ Cb, int M, int ntiles)
{
    __shared__ float red[128];

    const int t = threadIdx.x;
    const int wave = t >> 6;
    const int lane = t & 63;
    const int m16 = lane & 15;
    const int quad = lane >> 4;
    const int k0 = quad * 8;
    const int colbase = wave * 32;

    const bf16x8 zero8 = {0, 0, 0, 0, 0, 0, 0, 0};

    bf16x8 w1f[2][4], w2f[2][4];
#pragma unroll
    for (int ct = 0; ct < 2; ct++) {
        int col = colbase + ct * 16 + m16;
#pragma unroll
        for (int kc = 0; kc < 4; kc++) {
            w1f[ct][kc] = *(const bf16x8*)(W1t + (size_t)col * 128 + kc * 32 + k0);
            w2f[ct][kc] = *(const bf16x8*)(W2t + (size_t)col * 128 + kc * 32 + k0);
        }
    }
    f32x4 bs[2];
#pragma unroll
    for (int ct = 0; ct < 2; ct++)
        bs[ct] = *(const f32x4*)(bias + colbase + ct * 16 + quad * 4);

    float psum[2][4], psq[2][4];
#pragma unroll
    for (int ct = 0; ct < 2; ct++)
#pragma unroll
        for (int r = 0; r < 4; r++) { psum[ct][r] = 0.f; psq[ct][r] = 0.f; }

    bf16x8 a1[4], a2[4], a1n[4], a2n[4];

    int tile = blockIdx.x;
    if (tile < ntiles) {
        int arow = tile * 16 + m16;
        bool aok = arow < M;
#pragma unroll
        for (int kc = 0; kc < 4; kc++) {
            a1[kc] = aok ? *(const bf16x8*)(A1 + (size_t)arow * 128 + kc * 32 + k0) : zero8;
            a2[kc] = aok ? *(const bf16x8*)(A2 + (size_t)arow * 128 + kc * 32 + k0) : zero8;
        }
    }

    for (; tile < ntiles; tile += gridDim.x) {
        int nt = tile + gridDim.x;
        if (nt < ntiles) {
            int arow = nt * 16 + m16;
            bool aok = arow < M;
#pragma unroll
            for (int kc = 0; kc < 4; kc++) {
                a1n[kc] = aok ? *(const bf16x8*)(A1 + (size_t)arow * 128 + kc * 32 + k0) : zero8;
                a2n[kc] = aok ? *(const bf16x8*)(A2 + (size_t)arow * 128 + kc * 32 + k0) : zero8;
            }
        }

        f32x4 acc[2];
        acc[0] = (f32x4){0.f, 0.f, 0.f, 0.f};
        acc[1] = (f32x4){0.f, 0.f, 0.f, 0.f};
#pragma unroll
        for (int kc = 0; kc < 4; kc++) {
#pragma unroll
            for (int ct = 0; ct < 2; ct++) {
                acc[ct] = __builtin_amdgcn_mfma_f32_16x16x32_bf16(w1f[ct][kc], a1[kc], acc[ct], 0, 0, 0);
                acc[ct] = __builtin_amdgcn_mfma_f32_16x16x32_bf16(w2f[ct][kc], a2[kc], acc[ct], 0, 0, 0);
            }
        }

        int orow = tile * 16 + m16;
        if (orow < M) {
#pragma unroll
            for (int ct = 0; ct < 2; ct++) {
                f32x4 v = acc[ct] + bs[ct];
                int col = colbase + ct * 16 + quad * 4;
#pragma unroll
                for (int r = 0; r < 4; r++) { psum[ct][r] += v[r]; psq[ct][r] += v[r] * v[r]; }
                ushort4 o;
                o.x = f2b(v[0]); o.y = f2b(v[1]); o.z = f2b(v[2]); o.w = f2b(v[3]);
                *(ushort4*)(Cb + (size_t)orow * 128 + col) = o;
            }
        }

        if (nt < ntiles) {
            a1[0] = a1n[0]; a1[1] = a1n[1]; a1[2] = a1n[2]; a1[3] = a1n[3];
            a2[0] = a2n[0]; a2[1] = a2n[1]; a2[2] = a2n[2]; a2[3] = a2n[3];
        }
    }

#pragma unroll
    for (int ct = 0; ct < 2; ct++)
#pragma unroll
        for (int r = 0; r < 4; r++) {
#pragma unroll
            for (int mask = 1; mask <= 8; mask <<= 1) {
                psum[ct][r] += __shfl_xor(psum[ct][r], mask, 64);
                psq[ct][r]  += __shfl_xor(psq[ct][r], mask, 64);
            }
        }
    if (m16 == 0) {
#pragma unroll
        for (int ct = 0; ct < 2; ct++)
#pragma unroll
            for (int r = 0; r < 4; r++)
                red[colbase + ct * 16 + quad * 4 + r] = psum[ct][r];
    }
    __syncthreads();
    if (t < 128) atomicAdd(&stats[t], red[t]);
    __syncthreads();
    if (m16 == 0) {
#pragma unroll
        for (int ct = 0; ct < 2; ct++)
#pragma unroll
            for (int r = 0; r < 4; r++)
                red[colbase + ct * 16 + quad * 4 + r] = psq[ct][r];
    }
    __syncthreads();
    if (t < 128) atomicAdd(&stats[128 + t], red[t]);
}

// ---------------------------------------------------------------------------
// global mean pool: BN affine from stats, relu, mean.
// v2: 16B/lane loads — 8 row-groups x 16 lanes, LDS cross-group reduce.
// ---------------------------------------------------------------------------
__global__ __launch_bounds__(128) void pool_mean_kernel(const unsigned short* __restrict__ h,
                                                        const int* __restrict__ gstart,
                                                        const float* __restrict__ stats,
                                                        const float* __restrict__ gamma,
                                                        const float* __restrict__ beta,
                                                        float* __restrict__ out) {
    __shared__ float red[8][128];
    int g = blockIdx.x;
    int t = threadIdx.x;
    int lane = t & 15, grp = t >> 4;
    int c0 = lane * 8;
    float c[8], b[8];
#pragma unroll
    for (int j = 0; j < 8; j++) {
        int col = c0 + j;
        float mu = stats[col] * INV_N;
        float var = stats[128 + col] * INV_N - mu * mu;
        float rs = rsqrtf(var + BN_EPS);
        c[j] = gamma[col] * rs;
        b[j] = beta[col] - mu * c[j];
    }
    int beg = gstart[g];
    int end = gstart[g + 1];
    float s[8];
#pragma unroll
    for (int j = 0; j < 8; j++) s[j] = 0.f;
    for (int i = beg + grp; i < end; i += 8) {
        bf16x8 v = *(const bf16x8*)(h + (size_t)i * 128 + c0);
#pragma unroll
        for (int j = 0; j < 8; j++)
            s[j] += fmaxf(b2f((unsigned short)v[j]) * c[j] + b[j], 0.f);
    }
#pragma unroll
    for (int j = 0; j < 8; j++) red[grp][c0 + j] = s[j];
    __syncthreads();
    if (t < 16) {
        float cnt = fmaxf((float)(end - beg), 1.0f);
        int cc0 = t * 8;
#pragma unroll
        for (int j = 0; j < 8; j++) {
            float tot = 0.f;
#pragma unroll
            for (int r = 0; r < 8; r++) tot += red[r][cc0 + j];
            out[(size_t)g * 128 + cc0 + j] = tot / cnt;
        }
    }
}

// ---------------------------------------------------------------------------
extern "C" void kernel_launch(void* const* d_in, const int* in_sizes, int n_in,
                              void* d_out, int out_size, void* d_ws, size_t ws_size,
                              hipStream_t stream) {
    const float* x    = (const float*)d_in[0];
    const int*   ei   = (const int*)d_in[1];
    const int*   src  = ei;
    const int*   dst  = ei + N_EDGES;
    const int*   batch = (const int*)d_in[2];
    const float* gw1  = (const float*)d_in[3];
    const float* gb1  = (const float*)d_in[4];
    const float* gw2  = (const float*)d_in[5];
    const float* gb2  = (const float*)d_in[6];
    const float* swl  = (const float*)d_in[7];
    const float* sbl  = (const float*)d_in[8];
    const float* swr  = (const float*)d_in[9];
    const float* bng  = (const float*)d_in[10];
    const float* bnb  = (const float*)d_in[11];
    float* out = (float*)d_out;

    // workspace layout (float units; bf16 buffers 16B-aligned)
    float* ws = (float*)d_ws;
    unsigned short* x16    = (unsigned short*)(ws + 0);
    unsigned short* agg16  = (unsigned short*)(ws + 3200000);
    unsigned short* hact16 = (unsigned short*)(ws + 6400000);
    unsigned short* hpre16 = (unsigned short*)(ws + 9600000);
    unsigned short* wt     = (unsigned short*)(ws + 12800000);  // 6*16384 u16
    float*          inv_deg= ws + 12850000;                     // 50000
    int*            row_beg= (int*)(ws + 12900000);             // 50000
    int*            cursor = (int*)(ws + 12950000);             // 50000 | total | stats(768)
    int*            total  = cursor + 50000;
    float*          stats  = (float*)(cursor + 50001);          // 3*256
    unsigned short* csr_src= (unsigned short*)(ws + 13100000);  // 600000 u16
    int*            gstart = (int*)(ws + 13700000);             // 513

    const int aggr_blocks = (N_NODES + 15) / 16;                // 3125 (16 nodes/block)
    const int ntiles32 = (N_NODES + 31) / 32;                   // 1563
    const int ntiles16 = (N_NODES + 15) / 16;                   // 3125
    const int ggrid = 512;

    // ---- init: cursor + total + stats in one memset ----
    hipMemsetAsync(cursor, 0, (50001 + 768) * sizeof(int), stream);

    // ---- prep: x->bf16, weights->bf16^T, degree count ----
    prep_kernel<<<CONVX_BLOCKS + WCONV_BLOCKS + DEG_BLOCKS, 256, 0, stream>>>(
        x, gw1, gw2, swl, swr, dst, x16, wt, cursor);

    // ---- CSR ----
    alloc_kernel<<<ALLOC_BLOCKS + 3, 256, 0, stream>>>(cursor, row_beg, inv_deg, total, batch, gstart);
    csr_fill_kernel<<<(N_EDGES + 255) / 256, 256, 0, stream>>>(src, dst, cursor, csr_src, N_EDGES);

    // ---- GIN ----
    aggregate_kernel<false, false, false><<<aggr_blocks, 256, 0, stream>>>(
        x16, row_beg, cursor, csr_src, nullptr, nullptr, nullptr, nullptr, agg16, nullptr, N_NODES);
    gemm_gin_kernel<<<ggrid, 256, 0, stream>>>(
        x16, agg16, wt + 0 * 16384, wt + 1 * 16384, gb1, gb2, stats + 0, hpre16, N_NODES, ntiles32);

    // ---- SAGE 0 ----
    aggregate_kernel<true, true, true><<<aggr_blocks, 256, 0, stream>>>(
        hpre16, row_beg, cursor, csr_src, stats + 0, bng + 0 * HID, bnb + 0 * HID, inv_deg,
        agg16, hact16, N_NODES);
    gemm_dual_kernel<<<ggrid, 256, 0, stream>>>(
        agg16, hact16, wt + 2 * 16384, wt + 3 * 16384, sbl + 0 * HID, stats + 256, hpre16, N_NODES, ntiles16);

    // ---- SAGE 1 ----
    aggregate_kernel<true, true, true><<<aggr_blocks, 256, 0, stream>>>(
        hpre16, row_beg, cursor, csr_src, stats + 256, bng + 1 * HID, bnb + 1 * HID, inv_deg,
        agg16, hact16, N_NODES);
    gemm_dual_kernel<<<ggrid, 256, 0, stream>>>(
        agg16, hact16, wt + 4 * 16384, wt + 5 * 16384, sbl + 1 * HID, stats + 512, hpre16, N_NODES, ntiles16);

    // ---- pool (BN2 affine folded) ----
    pool_mean_kernel<<<N_GRAPHS, 128, 0, stream>>>(
        hpre16, gstart, stats + 512, bng + 2 * HID, bnb + 2 * HID, out);
}

// Round 2
// 313.658 us; speedup vs baseline: 1.1576x; 1.1122x over previous
//
#include <hip/hip_runtime.h>

#define N_NODES 50000
#define N_EDGES 600000
#define HID 128
#define N_GRAPHS 512
#define BN_EPS 1e-5f
#define INV_N (1.0f / 50000.0f)
#define NGROUPS 3125            // 50000 / 16, exact
#define FUSED_GRID 1024
#define IDXCAP 2048

typedef __attribute__((ext_vector_type(8))) short bf16x8;
typedef __attribute__((ext_vector_type(4))) float f32x4;

__device__ __forceinline__ unsigned short f2b(float f) {
    unsigned u = __float_as_uint(f);
    return (unsigned short)((u + 0x7FFFu + ((u >> 16) & 1u)) >> 16);
}
__device__ __forceinline__ float b2f(unsigned short h) {
    return __uint_as_float(((unsigned)h) << 16);
}

// sum the 8 stats replicas
__device__ __forceinline__ float stats_sum(const float* __restrict__ s, int idx) {
    float v = 0.f;
#pragma unroll
    for (int r = 0; r < 8; r++) v += s[r * 256 + idx];
    return v;
}

// ---------------------------------------------------------------------------
// prep: convert x -> bf16 | transpose+convert 6 weight mats | degree count
// ---------------------------------------------------------------------------
#define CONVX_BLOCKS 6250
#define WCONV_BLOCKS 384
#define DEG_BLOCKS   2344
__global__ __launch_bounds__(256) void prep_kernel(
    const float* __restrict__ x, const float* __restrict__ gw1, const float* __restrict__ gw2,
    const float* __restrict__ swl, const float* __restrict__ swr, const int* __restrict__ dst,
    unsigned short* __restrict__ x16, unsigned short* __restrict__ wt, int* __restrict__ deg)
{
    int b = blockIdx.x;
    int t = threadIdx.x;
    if (b < CONVX_BLOCKS) {
        int gid = b * 256 + t;
        int i = gid >> 5, l = gid & 31;
        if (i >= N_NODES) return;
        int c0 = l * 4;
        float4 v = *(const float4*)(x + (size_t)i * 128 + c0);
        ushort4 o;
        o.x = f2b(v.x); o.y = f2b(v.y); o.z = f2b(v.z); o.w = f2b(v.w);
        *(ushort4*)(x16 + (size_t)i * 128 + c0) = o;
    } else if (b < CONVX_BLOCKS + WCONV_BLOCKS) {
        int gid = (b - CONVX_BLOCKS) * 256 + t;   // < 6*16384
        int m = gid >> 14;
        int e = gid & 16383;
        int k = e >> 7;
        int n = e & 127;
        const float* src = (m == 0) ? gw1 : (m == 1) ? gw2 : (m == 2) ? swl
                         : (m == 3) ? swr : (m == 4) ? (swl + 16384) : (swr + 16384);
        wt[m * 16384 + n * 128 + k] = f2b(src[k * 128 + n]);
    } else {
        int e = (b - CONVX_BLOCKS - WCONV_BLOCKS) * 256 + t;
        if (e < N_EDGES) atomicAdd(&deg[dst[e]], 1);
    }
}

// ---------------------------------------------------------------------------
// alloc (per-block scan + atomic base) + gstart (binary search), fused
// ---------------------------------------------------------------------------
#define ALLOC_BLOCKS 196
__global__ __launch_bounds__(256) void alloc_kernel(int* __restrict__ cursor,
                                                    int* __restrict__ row_beg,
                                                    float* __restrict__ inv_deg,
                                                    int* __restrict__ total,
                                                    const int* __restrict__ batch,
                                                    int* __restrict__ gstart) {
    if (blockIdx.x >= ALLOC_BLOCKS) {
        int g = (blockIdx.x - ALLOC_BLOCKS) * 256 + threadIdx.x;
        if (g > N_GRAPHS) return;
        int lo = 0, hi = N_NODES;
        while (lo < hi) {
            int mid = (lo + hi) >> 1;
            if (batch[mid] < g) lo = mid + 1; else hi = mid;
        }
        gstart[g] = lo;
        return;
    }
    __shared__ int tmp[256];
    __shared__ int base;
    int i = blockIdx.x * 256 + threadIdx.x;
    int d = (i < N_NODES) ? cursor[i] : 0;
    tmp[threadIdx.x] = d;
    __syncthreads();
#pragma unroll
    for (int off = 1; off < 256; off <<= 1) {
        int v = (threadIdx.x >= off) ? tmp[threadIdx.x - off] : 0;
        __syncthreads();
        tmp[threadIdx.x] += v;
        __syncthreads();
    }
    if (threadIdx.x == 255) base = atomicAdd(total, tmp[255]);
    __syncthreads();
    if (i < N_NODES) {
        int b = base + tmp[threadIdx.x] - d;
        row_beg[i] = b;
        cursor[i] = b;
        inv_deg[i] = 1.0f / fmaxf((float)d, 1.0f);
    }
}

__global__ void csr_fill_kernel(const int* __restrict__ src, const int* __restrict__ dst,
                                int* __restrict__ cursor, unsigned short* __restrict__ csr_src, int nE) {
    int e = blockIdx.x * blockDim.x + threadIdx.x;
    if (e < nE) {
        int pos = atomicAdd(&cursor[dst[e]], 1);
        csr_src[pos] = (unsigned short)src[e];
    }
}

// ---------------------------------------------------------------------------
// gather one node-row slice (8 cols per lane): a[j] = sum_e act(feat[src][c0+j])
// ---------------------------------------------------------------------------
template<bool AFF>
__device__ __forceinline__ void gather_row(
    const unsigned short* __restrict__ feat,
    const unsigned short* __restrict__ csr_src,
    const unsigned short* __restrict__ idxbuf,
    bool lds_ok, int ebeg, int beg, int deg, int c0,
    const float (&cc)[8], const float (&ss)[8], float (&a)[8])
{
#pragma unroll
    for (int j = 0; j < 8; j++) a[j] = 0.f;
    if (lds_ok) {
        const int off = beg - ebeg;
        int e = 0;
        for (; e + 7 < deg; e += 8) {
            int s[8];
#pragma unroll
            for (int u = 0; u < 8; u++) s[u] = idxbuf[off + e + u];
            bf16x8 v[8];
#pragma unroll
            for (int u = 0; u < 8; u++)
                v[u] = *(const bf16x8*)(feat + (size_t)s[u] * 128 + c0);
#pragma unroll
            for (int u = 0; u < 8; u++)
#pragma unroll
                for (int j = 0; j < 8; j++) {
                    float tv = b2f((unsigned short)v[u][j]);
                    if (AFF) tv = fmaxf(tv * cc[j] + ss[j], 0.f);
                    a[j] += tv;
                }
        }
        for (; e + 3 < deg; e += 4) {
            int s[4];
#pragma unroll
            for (int u = 0; u < 4; u++) s[u] = idxbuf[off + e + u];
            bf16x8 v[4];
#pragma unroll
            for (int u = 0; u < 4; u++)
                v[u] = *(const bf16x8*)(feat + (size_t)s[u] * 128 + c0);
#pragma unroll
            for (int u = 0; u < 4; u++)
#pragma unroll
                for (int j = 0; j < 8; j++) {
                    float tv = b2f((unsigned short)v[u][j]);
                    if (AFF) tv = fmaxf(tv * cc[j] + ss[j], 0.f);
                    a[j] += tv;
                }
        }
        for (; e < deg; e++) {
            int s0 = idxbuf[off + e];
            bf16x8 v0 = *(const bf16x8*)(feat + (size_t)s0 * 128 + c0);
#pragma unroll
            for (int j = 0; j < 8; j++) {
                float tv = b2f((unsigned short)v0[j]);
                if (AFF) tv = fmaxf(tv * cc[j] + ss[j], 0.f);
                a[j] += tv;
            }
        }
    } else {
        // pathological skew fallback (never triggers for this graph)
        for (int e = beg; e < beg + deg; e++) {
            int s0 = csr_src[e];
            bf16x8 v0 = *(const bf16x8*)(feat + (size_t)s0 * 128 + c0);
#pragma unroll
            for (int j = 0; j < 8; j++) {
                float tv = b2f((unsigned short)v0[j]);
                if (AFF) tv = fmaxf(tv * cc[j] + ss[j], 0.f);
                a[j] += tv;
            }
        }
    }
}

// ---------------------------------------------------------------------------
// Fused GIN: per 16-node group: gather neighbors of x, A = x + agg,
// Hout = bf16( relu(A@W1+b1) @ W2 + b2 ), stats (8-replica) accumulated.
// Block: 256 thr. Gather role: (nslot = t>>4, c0 = (t&15)*8).
// GEMM role: wave covers cols [wave*32, wave*32+32), swapped-operand MFMA.
// ---------------------------------------------------------------------------
__global__ __launch_bounds__(256, 2) void fused_gin_kernel(
    const unsigned short* __restrict__ X,
    const int* __restrict__ row_beg, const int* __restrict__ row_end,
    const unsigned short* __restrict__ csr_src,
    const unsigned short* __restrict__ W1t, const unsigned short* __restrict__ W2t,
    const float* __restrict__ b1, const float* __restrict__ b2,
    float* __restrict__ stats_out, unsigned short* __restrict__ Hout, int ngroups)
{
    __shared__ unsigned short idxbuf[IDXCAP];
    __shared__ unsigned short aT[16][136];
    __shared__ unsigned short t1[16][136];
    __shared__ float red[128];

    const int t = threadIdx.x;
    const int wave = t >> 6;
    const int lane = t & 63;
    const int m16 = lane & 15;
    const int quad = lane >> 4;
    const int k0 = quad * 8;
    const int colbase = wave * 32;
    const int nslot = t >> 4;
    const int c0 = (t & 15) * 8;

    bf16x8 w1f[2][4], w2f[2][4];
#pragma unroll
    for (int ct = 0; ct < 2; ct++) {
        int col = colbase + ct * 16 + m16;
#pragma unroll
        for (int kc = 0; kc < 4; kc++) {
            w1f[ct][kc] = *(const bf16x8*)(W1t + (size_t)col * 128 + kc * 32 + k0);
            w2f[ct][kc] = *(const bf16x8*)(W2t + (size_t)col * 128 + kc * 32 + k0);
        }
    }
    f32x4 bs1[2], bs2[2];
#pragma unroll
    for (int ct = 0; ct < 2; ct++) {
        bs1[ct] = *(const f32x4*)(b1 + colbase + ct * 16 + quad * 4);
        bs2[ct] = *(const f32x4*)(b2 + colbase + ct * 16 + quad * 4);
    }

    float psum[2][4], psq[2][4];
#pragma unroll
    for (int ct = 0; ct < 2; ct++)
#pragma unroll
        for (int r = 0; r < 4; r++) { psum[ct][r] = 0.f; psq[ct][r] = 0.f; }

    float dcc[8], dss[8];   // dummies for AFF=false path
#pragma unroll
    for (int j = 0; j < 8; j++) { dcc[j] = 0.f; dss[j] = 0.f; }

    for (int g = blockIdx.x; g < ngroups; g += gridDim.x) {
        const int node0 = g * 16;
        const int node = node0 + nslot;
        const int ebeg = row_beg[node0];
        const int ecnt = row_end[node0 + 15] - ebeg;
        const bool lds_ok = (ecnt <= IDXCAP);
        if (lds_ok)
            for (int i = t; i < ecnt; i += 256) idxbuf[i] = csr_src[ebeg + i];
        bf16x8 vself = *(const bf16x8*)(X + (size_t)node * 128 + c0);
        const int beg = row_beg[node];
        const int deg = row_end[node] - beg;
        __syncthreads();   // idxbuf ready; prev-iter LDS reads done

        float a[8];
        gather_row<false>(X, csr_src, idxbuf, lds_ok, ebeg, beg, deg, c0, dcc, dss, a);

        bf16x8 arow;
#pragma unroll
        for (int j = 0; j < 8; j++)
            arow[j] = (short)f2b(a[j] + b2f((unsigned short)vself[j]));
        *(bf16x8*)&aT[nslot][c0] = arow;
        __syncthreads();   // aT ready

        // stage 1: T1 = relu(A@W1 + b1)
        bf16x8 af[4];
#pragma unroll
        for (int kc = 0; kc < 4; kc++)
            af[kc] = *(const bf16x8*)&aT[m16][kc * 32 + k0];
        f32x4 acc[2];
        acc[0] = (f32x4){0.f, 0.f, 0.f, 0.f};
        acc[1] = (f32x4){0.f, 0.f, 0.f, 0.f};
#pragma unroll
        for (int kc = 0; kc < 4; kc++)
#pragma unroll
            for (int ct = 0; ct < 2; ct++)
                acc[ct] = __builtin_amdgcn_mfma_f32_16x16x32_bf16(w1f[ct][kc], af[kc], acc[ct], 0, 0, 0);
#pragma unroll
        for (int ct = 0; ct < 2; ct++) {
            f32x4 v = acc[ct] + bs1[ct];
            ushort4 o;
            o.x = f2b(fmaxf(v[0], 0.f));
            o.y = f2b(fmaxf(v[1], 0.f));
            o.z = f2b(fmaxf(v[2], 0.f));
            o.w = f2b(fmaxf(v[3], 0.f));
            *(ushort4*)&t1[m16][colbase + ct * 16 + quad * 4] = o;
        }
        __syncthreads();   // t1 ready

        // stage 2: out = T1@W2 + b2
        bf16x8 tf[4];
#pragma unroll
        for (int kc = 0; kc < 4; kc++)
            tf[kc] = *(const bf16x8*)&t1[m16][kc * 32 + k0];
        f32x4 acc2[2];
        acc2[0] = (f32x4){0.f, 0.f, 0.f, 0.f};
        acc2[1] = (f32x4){0.f, 0.f, 0.f, 0.f};
#pragma unroll
        for (int kc = 0; kc < 4; kc++)
#pragma unroll
            for (int ct = 0; ct < 2; ct++)
                acc2[ct] = __builtin_amdgcn_mfma_f32_16x16x32_bf16(w2f[ct][kc], tf[kc], acc2[ct], 0, 0, 0);

        const int orow = node0 + m16;
#pragma unroll
        for (int ct = 0; ct < 2; ct++) {
            f32x4 v = acc2[ct] + bs2[ct];
            int col = colbase + ct * 16 + quad * 4;
#pragma unroll
            for (int r = 0; r < 4; r++) { psum[ct][r] += v[r]; psq[ct][r] += v[r] * v[r]; }
            ushort4 o;
            o.x = f2b(v[0]); o.y = f2b(v[1]); o.z = f2b(v[2]); o.w = f2b(v[3]);
            *(ushort4*)(Hout + (size_t)orow * 128 + col) = o;
        }
    }

    // stats flush (8-replica to cut atomic chains)
#pragma unroll
    for (int ct = 0; ct < 2; ct++)
#pragma unroll
        for (int r = 0; r < 4; r++)
#pragma unroll
            for (int mask = 1; mask <= 8; mask <<= 1) {
                psum[ct][r] += __shfl_xor(psum[ct][r], mask, 64);
                psq[ct][r]  += __shfl_xor(psq[ct][r], mask, 64);
            }
    __syncthreads();
    if (m16 == 0)
#pragma unroll
        for (int ct = 0; ct < 2; ct++)
#pragma unroll
            for (int r = 0; r < 4; r++)
                red[colbase + ct * 16 + quad * 4 + r] = psum[ct][r];
    __syncthreads();
    if (t < 128) atomicAdd(&stats_out[(blockIdx.x & 7) * 256 + t], red[t]);
    __syncthreads();
    if (m16 == 0)
#pragma unroll
        for (int ct = 0; ct < 2; ct++)
#pragma unroll
            for (int r = 0; r < 4; r++)
                red[colbase + ct * 16 + quad * 4 + r] = psq[ct][r];
    __syncthreads();
    if (t < 128) atomicAdd(&stats_out[(blockIdx.x & 7) * 256 + 128 + t], red[t]);
}

// ---------------------------------------------------------------------------
// Fused SAGE layer: per 16-node group: act(v)=relu(v*c+s) from stats_in,
// agg = mean_nb act(h), hact = act(h_self),
// Hout = bf16( agg@Wl + hact@Wr + bias ), stats_out (8-replica).
// Ping-pong: Hin != Hout (blocks race otherwise).
// ---------------------------------------------------------------------------
__global__ __launch_bounds__(256, 2) void fused_sage_kernel(
    const unsigned short* __restrict__ Hin,
    const int* __restrict__ row_beg, const int* __restrict__ row_end,
    const unsigned short* __restrict__ csr_src,
    const float* __restrict__ stats_in, const float* __restrict__ gamma,
    const float* __restrict__ beta, const float* __restrict__ inv_deg,
    const unsigned short* __restrict__ Wlt, const unsigned short* __restrict__ Wrt,
    const float* __restrict__ bias, float* __restrict__ stats_out,
    unsigned short* __restrict__ Hout, int ngroups)
{
    __shared__ unsigned short idxbuf[IDXCAP];
    __shared__ unsigned short aT[16][136];
    __shared__ unsigned short hT[16][136];
    __shared__ float red[128];

    const int t = threadIdx.x;
    const int wave = t >> 6;
    const int lane = t & 63;
    const int m16 = lane & 15;
    const int quad = lane >> 4;
    const int k0 = quad * 8;
    const int colbase = wave * 32;
    const int nslot = t >> 4;
    const int c0 = (t & 15) * 8;

    // BN affine for gather columns (stats finalized by previous kernel)
    float cc[8], ss[8];
#pragma unroll
    for (int j = 0; j < 8; j++) {
        int col = c0 + j;
        float mu = stats_sum(stats_in, col) * INV_N;
        float var = stats_sum(stats_in, 128 + col) * INV_N - mu * mu;
        float rs = rsqrtf(var + BN_EPS);
        float c = gamma[col] * rs;
        cc[j] = c;
        ss[j] = beta[col] - mu * c;
    }

    bf16x8 wl[2][4], wr[2][4];
#pragma unroll
    for (int ct = 0; ct < 2; ct++) {
        int col = colbase + ct * 16 + m16;
#pragma unroll
        for (int kc = 0; kc < 4; kc++) {
            wl[ct][kc] = *(const bf16x8*)(Wlt + (size_t)col * 128 + kc * 32 + k0);
            wr[ct][kc] = *(const bf16x8*)(Wrt + (size_t)col * 128 + kc * 32 + k0);
        }
    }
    f32x4 bs[2];
#pragma unroll
    for (int ct = 0; ct < 2; ct++)
        bs[ct] = *(const f32x4*)(bias + colbase + ct * 16 + quad * 4);

    float psum[2][4], psq[2][4];
#pragma unroll
    for (int ct = 0; ct < 2; ct++)
#pragma unroll
        for (int r = 0; r < 4; r++) { psum[ct][r] = 0.f; psq[ct][r] = 0.f; }

    for (int g = blockIdx.x; g < ngroups; g += gridDim.x) {
        const int node0 = g * 16;
        const int node = node0 + nslot;
        const int ebeg = row_beg[node0];
        const int ecnt = row_end[node0 + 15] - ebeg;
        const bool lds_ok = (ecnt <= IDXCAP);
        if (lds_ok)
            for (int i = t; i < ecnt; i += 256) idxbuf[i] = csr_src[ebeg + i];
        bf16x8 vself = *(const bf16x8*)(Hin + (size_t)node * 128 + c0);
        const float sc = inv_deg[node];
        const int beg = row_beg[node];
        const int deg = row_end[node] - beg;
        __syncthreads();   // idxbuf ready; prev-iter LDS reads done

        float a[8];
        gather_row<true>(Hin, csr_src, idxbuf, lds_ok, ebeg, beg, deg, c0, cc, ss, a);

        bf16x8 arow, hrow;
#pragma unroll
        for (int j = 0; j < 8; j++) {
            arow[j] = (short)f2b(a[j] * sc);
            hrow[j] = (short)f2b(fmaxf(b2f((unsigned short)vself[j]) * cc[j] + ss[j], 0.f));
        }
        *(bf16x8*)&aT[nslot][c0] = arow;
        *(bf16x8*)&hT[nslot][c0] = hrow;
        __syncthreads();   // tiles ready

        // dual GEMM from LDS tiles
        bf16x8 a1[4], a2[4];
#pragma unroll
        for (int kc = 0; kc < 4; kc++) {
            a1[kc] = *(const bf16x8*)&aT[m16][kc * 32 + k0];
            a2[kc] = *(const bf16x8*)&hT[m16][kc * 32 + k0];
        }
        f32x4 acc[2];
        acc[0] = (f32x4){0.f, 0.f, 0.f, 0.f};
        acc[1] = (f32x4){0.f, 0.f, 0.f, 0.f};
#pragma unroll
        for (int kc = 0; kc < 4; kc++)
#pragma unroll
            for (int ct = 0; ct < 2; ct++) {
                acc[ct] = __builtin_amdgcn_mfma_f32_16x16x32_bf16(wl[ct][kc], a1[kc], acc[ct], 0, 0, 0);
                acc[ct] = __builtin_amdgcn_mfma_f32_16x16x32_bf16(wr[ct][kc], a2[kc], acc[ct], 0, 0, 0);
            }

        const int orow = node0 + m16;
#pragma unroll
        for (int ct = 0; ct < 2; ct++) {
            f32x4 v = acc[ct] + bs[ct];
            int col = colbase + ct * 16 + quad * 4;
#pragma unroll
            for (int r = 0; r < 4; r++) { psum[ct][r] += v[r]; psq[ct][r] += v[r] * v[r]; }
            ushort4 o;
            o.x = f2b(v[0]); o.y = f2b(v[1]); o.z = f2b(v[2]); o.w = f2b(v[3]);
            *(ushort4*)(Hout + (size_t)orow * 128 + col) = o;
        }
    }

    // stats flush (8-replica)
#pragma unroll
    for (int ct = 0; ct < 2; ct++)
#pragma unroll
        for (int r = 0; r < 4; r++)
#pragma unroll
            for (int mask = 1; mask <= 8; mask <<= 1) {
                psum[ct][r] += __shfl_xor(psum[ct][r], mask, 64);
                psq[ct][r]  += __shfl_xor(psq[ct][r], mask, 64);
            }
    __syncthreads();
    if (m16 == 0)
#pragma unroll
        for (int ct = 0; ct < 2; ct++)
#pragma unroll
            for (int r = 0; r < 4; r++)
                red[colbase + ct * 16 + quad * 4 + r] = psum[ct][r];
    __syncthreads();
    if (t < 128) atomicAdd(&stats_out[(blockIdx.x & 7) * 256 + t], red[t]);
    __syncthreads();
    if (m16 == 0)
#pragma unroll
        for (int ct = 0; ct < 2; ct++)
#pragma unroll
            for (int r = 0; r < 4; r++)
                red[colbase + ct * 16 + quad * 4 + r] = psq[ct][r];
    __syncthreads();
    if (t < 128) atomicAdd(&stats_out[(blockIdx.x & 7) * 256 + 128 + t], red[t]);
}

// ---------------------------------------------------------------------------
// global mean pool: BN affine from (8-replica) stats, relu, mean.
// 16B/lane loads — 8 row-groups x 16 lanes, LDS cross-group reduce.
// ---------------------------------------------------------------------------
__global__ __launch_bounds__(128) void pool_mean_kernel(const unsigned short* __restrict__ h,
                                                        const int* __restrict__ gstart,
                                                        const float* __restrict__ stats,
                                                        const float* __restrict__ gamma,
                                                        const float* __restrict__ beta,
                                                        float* __restrict__ out) {
    __shared__ float red[8][128];
    int g = blockIdx.x;
    int t = threadIdx.x;
    int lane = t & 15, grp = t >> 4;
    int c0 = lane * 8;
    float c[8], b[8];
#pragma unroll
    for (int j = 0; j < 8; j++) {
        int col = c0 + j;
        float mu = stats_sum(stats, col) * INV_N;
        float var = stats_sum(stats, 128 + col) * INV_N - mu * mu;
        float rs = rsqrtf(var + BN_EPS);
        c[j] = gamma[col] * rs;
        b[j] = beta[col] - mu * c[j];
    }
    int beg = gstart[g];
    int end = gstart[g + 1];
    float s[8];
#pragma unroll
    for (int j = 0; j < 8; j++) s[j] = 0.f;
    for (int i = beg + grp; i < end; i += 8) {
        bf16x8 v = *(const bf16x8*)(h + (size_t)i * 128 + c0);
#pragma unroll
        for (int j = 0; j < 8; j++)
            s[j] += fmaxf(b2f((unsigned short)v[j]) * c[j] + b[j], 0.f);
    }
#pragma unroll
    for (int j = 0; j < 8; j++) red[grp][c0 + j] = s[j];
    __syncthreads();
    if (t < 16) {
        float cnt = fmaxf((float)(end - beg), 1.0f);
        int cc0 = t * 8;
#pragma unroll
        for (int j = 0; j < 8; j++) {
            float tot = 0.f;
#pragma unroll
            for (int r = 0; r < 8; r++) tot += red[r][cc0 + j];
            out[(size_t)g * 128 + cc0 + j] = tot / cnt;
        }
    }
}

// ---------------------------------------------------------------------------
extern "C" void kernel_launch(void* const* d_in, const int* in_sizes, int n_in,
                              void* d_out, int out_size, void* d_ws, size_t ws_size,
                              hipStream_t stream) {
    const float* x    = (const float*)d_in[0];
    const int*   ei   = (const int*)d_in[1];
    const int*   src  = ei;
    const int*   dst  = ei + N_EDGES;
    const int*   batch = (const int*)d_in[2];
    const float* gw1  = (const float*)d_in[3];
    const float* gb1  = (const float*)d_in[4];
    const float* gw2  = (const float*)d_in[5];
    const float* gb2  = (const float*)d_in[6];
    const float* swl  = (const float*)d_in[7];
    const float* sbl  = (const float*)d_in[8];
    const float* swr  = (const float*)d_in[9];
    const float* bng  = (const float*)d_in[10];
    const float* bnb  = (const float*)d_in[11];
    float* out = (float*)d_out;

    // workspace layout (float units; bf16 buffers 16B-aligned)
    float* ws = (float*)d_ws;
    unsigned short* x16    = (unsigned short*)(ws + 0);         // 50000*128 u16
    unsigned short* h_a    = (unsigned short*)(ws + 3200000);   // ping
    unsigned short* h_b    = (unsigned short*)(ws + 6400000);   // pong
    unsigned short* wt     = (unsigned short*)(ws + 12800000);  // 6*16384 u16
    float*          inv_deg= ws + 12850000;                     // 50000
    int*            row_beg= (int*)(ws + 12900000);             // 50000
    int*            cursor = (int*)(ws + 12950000);             // 50000 | total | stats(3*8*256)
    int*            total  = cursor + 50000;
    float*          stats  = (float*)(cursor + 50001);          // 3 layers x 8 replicas x 256
    unsigned short* csr_src= (unsigned short*)(ws + 13100000);  // 600000 u16
    int*            gstart = (int*)(ws + 13700000);             // 513

    // ---- init: cursor + total + stats in one memset ----
    hipMemsetAsync(cursor, 0, (50001 + 3 * 8 * 256) * sizeof(int), stream);

    // ---- prep: x->bf16, weights->bf16^T, degree count ----
    prep_kernel<<<CONVX_BLOCKS + WCONV_BLOCKS + DEG_BLOCKS, 256, 0, stream>>>(
        x, gw1, gw2, swl, swr, dst, x16, wt, cursor);

    // ---- CSR ----
    alloc_kernel<<<ALLOC_BLOCKS + 3, 256, 0, stream>>>(cursor, row_beg, inv_deg, total, batch, gstart);
    csr_fill_kernel<<<(N_EDGES + 255) / 256, 256, 0, stream>>>(src, dst, cursor, csr_src, N_EDGES);

    // ---- GIN (fused aggregate + MLP GEMM) ----
    fused_gin_kernel<<<FUSED_GRID, 256, 0, stream>>>(
        x16, row_beg, cursor, csr_src, wt + 0 * 16384, wt + 1 * 16384,
        gb1, gb2, stats + 0 * 2048, h_a, NGROUPS);

    // ---- SAGE 0 (fused) : h_a -> h_b ----
    fused_sage_kernel<<<FUSED_GRID, 256, 0, stream>>>(
        h_a, row_beg, cursor, csr_src, stats + 0 * 2048, bng + 0 * HID, bnb + 0 * HID,
        inv_deg, wt + 2 * 16384, wt + 3 * 16384, sbl + 0 * HID, stats + 1 * 2048, h_b, NGROUPS);

    // ---- SAGE 1 (fused) : h_b -> h_a ----
    fused_sage_kernel<<<FUSED_GRID, 256, 0, stream>>>(
        h_b, row_beg, cursor, csr_src, stats + 1 * 2048, bng + 1 * HID, bnb + 1 * HID,
        inv_deg, wt + 4 * 16384, wt + 5 * 16384, sbl + 1 * HID, stats + 2 * 2048, h_a, NGROUPS);

    // ---- pool (BN2 affine folded) ----
    pool_mean_kernel<<<N_GRAPHS, 128, 0, stream>>>(
        h_a, gstart, stats + 2 * 2048, bng + 2 * HID, bnb + 2 * HID, out);
}